// Round 1
// 419.342 us; speedup vs baseline: 1.1410x; 1.1410x over previous
//
#include <hip/hip_runtime.h>
#include <math.h>

// Problem constants
constexpr int BB = 2048;     // batch
constexpr int CC = 129;      // channels
constexpr int TT = 200;      // time
constexpr int NPAIR = BB * CC;          // 264192
constexpr int PPB = 64;                 // pairs per block (4 waves x 16 pairs)
constexpr int XSTR = 204;               // LDS x row stride (floats); 12p mod 32 -> 2-way only
constexpr int WSLICE = 16 * XSTR;       // per-wave LDS slice (floats) = 3264

// d_ws layout (in floats)
constexpr int OFF_AVG = 8192;           // B-frags occupy 16384 bf16 = 8192 floats
constexpr int OFF_MX  = OFF_AVG + NPAIR;
constexpr int OFF_FT  = OFF_MX + NPAIR; // NPAIR*4 floats

typedef __bf16 bf16x8 __attribute__((ext_vector_type(8)));
typedef float  f32x4  __attribute__((ext_vector_type(4)));

union BFU { int4 v; bf16x8 b; };
union BSU { __bf16 b; unsigned short u; };

// ---------------------------------------------------------------------------
// kInit: build W (128 k-rows x 64 n-cols) as MFMA B-fragments, split bf16
// hi/lo, pre-swizzled in fragment order:
//   bfr[((ks*4+nt)*2+h)*512 + lane*8 + i]  (ushort)
// Element (ks,nt,h,lane,i) = W[k = ks*32 + (lane>>4)*8 + i][n = nt*16 + (lane&15)]
//   n<60: bin kb=(n>>1)+1, even n -> w[t]*cos, odd n -> w[t]*sin
//   n==60: 1/100 (k<100)  -> GEMM emits segment mean (detrend + avg for free)
//   k>=100 or n>60: 0 (K padding / unused cols)
// ---------------------------------------------------------------------------
__global__ void kInit(unsigned short* __restrict__ bfr) {
    int tid = blockIdx.x * 256 + threadIdx.x;
    if (tid >= 16384) return;
    int i    = tid & 7;
    int lane = (tid >> 3) & 63;
    int h    = (tid >> 9) & 1;
    int nt   = (tid >> 10) & 3;
    int ks   = tid >> 12;
    int k = ks * 32 + (lane >> 4) * 8 + i;
    int n = nt * 16 + (lane & 15);
    float v = 0.f;
    if (k < 100) {
        if (n < 60) {
            int kb = (n >> 1) + 1;
            const float C = 0.06283185307179587f;      // 2*pi/100
            float w = 0.5f - 0.5f * cosf(C * (float)k);
            int ph = (kb * k) % 100;                   // exact phase reduction
            float ang = C * (float)ph;
            v = w * ((n & 1) ? sinf(ang) : cosf(ang));
        } else if (n == 60) {
            v = 0.01f;
        }
    }
    __bf16 hb = (__bf16)v;
    BSU out;
    if (h == 0) out.b = hb;
    else        out.b = (__bf16)(v - (float)hb);
    bfr[tid] = out.u;
}

// ---------------------------------------------------------------------------
// Kernel A v2: fully wave-autonomous Welch via split-bf16 MFMA GEMM.
//
// Key change vs v1: wave w owns exactly pairs [16w,16w+16) = seg-rows
// [48w,48w+48) = M-tiles 3w..3w+2. No cross-wave data sharing exists, so
// ALL __syncthreads() are removed; each wave runs stage->MFMA->reduce
// independently. 12 independent waves/CU (launch_bounds(256,3), LDS
// 52224B*3 = 156.7KB) hide each other's latency.
//  - max pass fused into staging (in-register + shfl_xor)
//  - B table loaded ks-outer: only 8 frags (32 VGPR) live -> fits 3-block
//    register budget; same total load count as keeping it resident.
//  - ks=3 A-frag masked in-register (k=96..99 only) -> no LDS pad reads,
//    no zero-fill guards needed anywhere.
//  - band reduce balanced: lane (pair,q) handles 15 cols, branchless band
//    masks, shfl_xor(1,2) combine, float4 feat store.
// spec = Ah*Bh + Ah*Bl + Al*Bh  (~2^-18 relative error, unchanged).
// ---------------------------------------------------------------------------
__global__ __launch_bounds__(256, 3) void kA(const float* __restrict__ x,
                                             const unsigned short* __restrict__ bfr,
                                             float* __restrict__ avg,
                                             float* __restrict__ mxg,
                                             float* __restrict__ feat) {
    __shared__ __align__(16) float xs[4 * WSLICE];   // 52224 B

    const int tid  = threadIdx.x;
    const int blk  = blockIdx.x;
    const int wv   = tid >> 6;
    const int lane = tid & 63;

    float* wx = xs + wv * WSLICE;                    // wave-private slice

    // ---- stage 16 rows (wave-private) + fused row max ----
    {
        const int p = lane >> 2, q = lane & 3;       // 4 lanes per row
        const float* rowg = x + ((size_t)blk * PPB + wv * 16 + p) * TT;
        float* rowl = wx + p * XSTR;
        float m = -3.4e38f;
        #pragma unroll
        for (int j = 0; j < 13; j++) {
            int i4 = q + 4 * j;                      // float4 index 0..49
            if (i4 < 50) {
                float4 v = *(const float4*)(rowg + i4 * 4);
                *(float4*)(rowl + i4 * 4) = v;
                m = fmaxf(fmaxf(m, fmaxf(v.x, v.y)), fmaxf(v.z, v.w));
            }
        }
        m = fmaxf(m, __shfl_xor(m, 1, 64));
        m = fmaxf(m, __shfl_xor(m, 2, 64));
        if (q == 0) mxg[blk * PPB + wv * 16 + p] = m;
    }

    // ---- MFMA: 3 M-tiles per wave, ks-outer (8 B-frags live at a time) ----
    const int quad = lane >> 4, mrow = lane & 15;

    const float* abase[3];
    {
        #pragma unroll
        for (int mi = 0; mi < 3; mi++) {
            int lr = mi * 16 + mrow;                 // local seg-row 0..47
            int pl = lr / 3;
            int sg = lr - pl * 3;
            abase[mi] = wx + pl * XSTR + sg * 50;
        }
    }

    f32x4 acc[3][4];
    #pragma unroll
    for (int a = 0; a < 3; a++)
        #pragma unroll
        for (int b = 0; b < 4; b++) acc[a][b] = f32x4{0.f, 0.f, 0.f, 0.f};

    const int4* bg = (const int4*)bfr;
    #pragma unroll
    for (int ks = 0; ks < 4; ks++) {
        bf16x8 Bh[4], Bl[4];
        #pragma unroll
        for (int nt = 0; nt < 4; nt++) {
            BFU uh, ul;
            uh.v = bg[((ks * 4 + nt) * 2 + 0) * 64 + lane];
            ul.v = bg[((ks * 4 + nt) * 2 + 1) * 64 + lane];
            Bh[nt] = uh.b;
            Bl[nt] = ul.b;
        }
        #pragma unroll
        for (int mi = 0; mi < 3; mi++) {
            float f[8];
            if (ks < 3) {
                const float* s = abase[mi] + quad * 8 + ks * 32;   // max off 195, in-row
                float2 f0 = *(const float2*)(s);
                float2 f1 = *(const float2*)(s + 2);
                float2 f2 = *(const float2*)(s + 4);
                float2 f3 = *(const float2*)(s + 6);
                f[0] = f0.x; f[1] = f0.y; f[2] = f1.x; f[3] = f1.y;
                f[4] = f2.x; f[5] = f2.y; f[6] = f3.x; f[7] = f3.y;
            } else {
                // k = 96..127: only k=96..99 real (quad==0, f[0..3]); rest 0.
                const float* s = abase[mi] + 96;                   // max off 199, in-row
                float2 f0 = *(const float2*)(s);
                float2 f1 = *(const float2*)(s + 2);
                bool v0 = (quad == 0);
                f[0] = v0 ? f0.x : 0.f; f[1] = v0 ? f0.y : 0.f;
                f[2] = v0 ? f1.x : 0.f; f[3] = v0 ? f1.y : 0.f;
                f[4] = 0.f; f[5] = 0.f; f[6] = 0.f; f[7] = 0.f;
            }
            bf16x8 Ah, Al;
            #pragma unroll
            for (int i = 0; i < 8; i++) {
                __bf16 hb = (__bf16)f[i];
                Ah[i] = hb;
                Al[i] = (__bf16)(f[i] - (float)hb);
            }
            __builtin_amdgcn_s_setprio(1);
            #pragma unroll
            for (int nt = 0; nt < 4; nt++) {
                acc[mi][nt] = __builtin_amdgcn_mfma_f32_16x16x32_bf16(Al, Bh[nt], acc[mi][nt], 0, 0, 0);
                acc[mi][nt] = __builtin_amdgcn_mfma_f32_16x16x32_bf16(Ah, Bl[nt], acc[mi][nt], 0, 0, 0);
                acc[mi][nt] = __builtin_amdgcn_mfma_f32_16x16x32_bf16(Ah, Bh[nt], acc[mi][nt], 0, 0, 0);
            }
            __builtin_amdgcn_s_setprio(0);
        }
    }

    // ---- spec to wave-private LDS slice (overwrites own x; same-wave DS is
    //      in-order, no barrier needed). sp[local_row][66], rows 0..47. ----
    float* sp = wx;
    #pragma unroll
    for (int mi = 0; mi < 3; mi++)
        #pragma unroll
        for (int nt = 0; nt < 4; nt++) {
            int col = nt * 16 + mrow;
            #pragma unroll
            for (int i = 0; i < 4; i++)             // C/D: col=lane&15, row=quad*4+i
                sp[(mi * 16 + quad * 4 + i) * 66 + col] = acc[mi][nt][i];
        }

    // ---- band reduce: lane (p2,q) -> pair p2, cols [15q,15q+15), 3 segs ----
    {
        const int p2 = lane >> 2, q = lane & 3;
        const float* r0 = sp + p2 * 3 * 66;
        float s0 = 0.f, s1 = 0.f, s2 = 0.f, s3 = 0.f;
        float mu0 = 0.f, mu2 = 0.f;
        #pragma unroll
        for (int sg = 0; sg < 3; sg++) {
            const float* row = r0 + sg * 66;
            float mu = row[60];
            if (sg == 0) mu0 = mu;
            if (sg == 2) mu2 = mu;
            #pragma unroll
            for (int j = 0; j < 15; j++) {
                int c = q * 15 + j;                  // col 0..59
                float v = row[c];
                if (j == 0) v = (q == 0) ? (v + 25.f * mu) : v;   // detrend re(k=1)
                float v2 = v * v;
                // bands (cols): d:0..7  t:6..15  a:14..25  b:24..59 (bins 4/8/13 shared)
                s0 += (c <= 7) ? v2 : 0.f;
                s1 += (c >= 6 && c <= 15) ? v2 : 0.f;
                s2 += (c >= 14 && c <= 25) ? v2 : 0.f;
                s3 += (c >= 24) ? v2 : 0.f;
            }
        }
        s0 += __shfl_xor(s0, 1, 64); s1 += __shfl_xor(s1, 1, 64);
        s2 += __shfl_xor(s2, 1, 64); s3 += __shfl_xor(s3, 1, 64);
        s0 += __shfl_xor(s0, 2, 64); s1 += __shfl_xor(s1, 2, 64);
        s2 += __shfl_xor(s2, 2, 64); s3 += __shfl_xor(s3, 2, 64);
        if (q == 0) {
            int pg = blk * PPB + wv * 16 + p2;
            float4 fo;
            fo.x = s0 * (2.f / (11250.f * 4.f));
            fo.y = s1 * (2.f / (11250.f * 5.f));
            fo.z = s2 * (2.f / (11250.f * 6.f));
            fo.w = s3 * (2.f / (11250.f * 18.f));
            *(float4*)(feat + (size_t)pg * 4) = fo;
            avg[pg] = (mu0 + mu2) * 0.5f;
        }
    }
}

// ---------------------------------------------------------------------------
// Kernel B: attention + MLP head (unchanged).
// ---------------------------------------------------------------------------
__global__ __launch_bounds__(256, 8) void kB(const float* __restrict__ avg,
                                             const float* __restrict__ mxv,
                                             const float* __restrict__ feat,
                                             const float* __restrict__ w_att1,
                                             const float* __restrict__ w_att2,
                                             const float* __restrict__ w_bb,
                                             const float* __restrict__ b_bb,
                                             const float* __restrict__ w_fe1,
                                             const float* __restrict__ b_fe1,
                                             const float* __restrict__ w_fe2,
                                             const float* __restrict__ b_fe2,
                                             const float* __restrict__ w_h1,
                                             const float* __restrict__ b_h1,
                                             const float* __restrict__ w_h2,
                                             const float* __restrict__ b_h2,
                                             const float* __restrict__ w_h3,
                                             const float* __restrict__ b_h3,
                                             float* __restrict__ out) {
    __shared__ float s_avg[132], s_mx[132], s_fq[520];
    __shared__ float s_t1a[16], s_t1b[16], s_t1[16];
    __shared__ float s_v[132];
    __shared__ float s_tf[2][64];
    __shared__ float s_p1[2][128];
    __shared__ float s_f1[128];
    __shared__ float s_p2[4][64];
    __shared__ float s_h[128];
    __shared__ float s_pg1[2][128];
    __shared__ float s_g1[128];
    __shared__ float s_pg2[4][64];

    const int b = blockIdx.x;
    const int tid = threadIdx.x;

    for (int i = tid; i < 129; i += 256) { s_avg[i] = avg[b * 129 + i]; s_mx[i] = mxv[b * 129 + i]; }
    for (int i = tid; i < 516; i += 256) s_fq[i] = feat[(size_t)b * 516 + i];
    __syncthreads();

    if (tid < 32) {
        int h = tid & 15;
        const float* src = (tid >= 16) ? s_mx : s_avg;
        float acc = 0.f;
        #pragma unroll 4
        for (int c = 0; c < 129; c++) acc += src[c] * w_att1[c * 16 + h];
        ((tid >= 16) ? s_t1b : s_t1a)[h] = fmaxf(acc, 0.f);
    }
    __syncthreads();
    if (tid < 16) s_t1[tid] = s_t1a[tid] + s_t1b[tid];
    __syncthreads();

    if (tid < 129) {
        float l = 0.f;
        #pragma unroll
        for (int j = 0; j < 16; j++) l += s_t1[j] * w_att2[j * 129 + tid];
        s_v[tid] = s_avg[tid] / (1.f + expf(-l));
    }
    __syncthreads();

    if (tid < 128) {
        int o = tid & 63, ks = tid >> 6;
        int i0 = ks ? 65 : 0, i1 = ks ? 129 : 65;
        float acc = 0.f;
        #pragma unroll 4
        for (int i = i0; i < i1; i++) acc += s_v[i] * w_bb[i * 64 + o];
        s_tf[ks][o] = acc;
    }
    {
        int o = tid & 127, ks = tid >> 7;
        float acc = 0.f;
        #pragma unroll 4
        for (int i = ks * 258; i < ks * 258 + 258; i++) acc += s_fq[i] * w_fe1[i * 128 + o];
        s_p1[ks][o] = acc;
    }
    __syncthreads();
    if (tid < 64) s_h[tid] = fmaxf(s_tf[0][tid] + s_tf[1][tid] + b_bb[tid], 0.f);
    if (tid >= 128) { int o = tid - 128; s_f1[o] = fmaxf(s_p1[0][o] + s_p1[1][o] + b_fe1[o], 0.f); }
    __syncthreads();

    {
        int o = tid & 63, ks = tid >> 6;
        float acc = 0.f;
        #pragma unroll 4
        for (int i = ks * 32; i < ks * 32 + 32; i++) acc += s_f1[i] * w_fe2[i * 64 + o];
        s_p2[ks][o] = acc;
    }
    __syncthreads();
    if (tid < 64) s_h[64 + tid] = fmaxf(s_p2[0][tid] + s_p2[1][tid] + s_p2[2][tid] + s_p2[3][tid] + b_fe2[tid], 0.f);
    __syncthreads();

    {
        int o = tid & 127, ks = tid >> 7;
        float acc = 0.f;
        #pragma unroll 4
        for (int i = ks * 64; i < ks * 64 + 64; i++) acc += s_h[i] * w_h1[i * 128 + o];
        s_pg1[ks][o] = acc;
    }
    __syncthreads();
    if (tid < 128) s_g1[tid] = fmaxf(s_pg1[0][tid] + s_pg1[1][tid] + b_h1[tid], 0.f);
    __syncthreads();

    {
        int o = tid & 63, ks = tid >> 6;
        float acc = 0.f;
        #pragma unroll 4
        for (int i = ks * 32; i < ks * 32 + 32; i++) acc += s_g1[i] * w_h2[i * 64 + o];
        s_pg2[ks][o] = acc;
    }
    __syncthreads();

    if (tid < 64) {
        float g2 = fmaxf(s_pg2[0][tid] + s_pg2[1][tid] + s_pg2[2][tid] + s_pg2[3][tid] + b_h2[tid], 0.f);
        float pz = g2 * w_h3[tid];
        for (int off = 32; off >= 1; off >>= 1) pz += __shfl_xor(pz, off, 64);
        if (tid == 0) out[b] = pz + b_h3[0];
    }
}

// ---------------------------------------------------------------------------
extern "C" void kernel_launch(void* const* d_in, const int* in_sizes, int n_in,
                              void* d_out, int out_size, void* d_ws, size_t ws_size,
                              hipStream_t stream) {
    const float* x      = (const float*)d_in[0];
    const float* w_att1 = (const float*)d_in[1];
    const float* w_att2 = (const float*)d_in[2];
    const float* w_bb   = (const float*)d_in[3];
    const float* b_bb   = (const float*)d_in[4];
    const float* w_fe1  = (const float*)d_in[5];
    const float* b_fe1  = (const float*)d_in[6];
    const float* w_fe2  = (const float*)d_in[7];
    const float* b_fe2  = (const float*)d_in[8];
    const float* w_h1   = (const float*)d_in[9];
    const float* b_h1   = (const float*)d_in[10];
    const float* w_h2   = (const float*)d_in[11];
    const float* b_h2   = (const float*)d_in[12];
    const float* w_h3   = (const float*)d_in[13];
    const float* b_h3   = (const float*)d_in[14];

    float* ws = (float*)d_ws;
    unsigned short* bfr = (unsigned short*)ws;     // 16384 bf16 = 8192 floats
    float* avg = ws + OFF_AVG;
    float* mxv = ws + OFF_MX;
    float* feat = ws + OFF_FT;

    kInit<<<64, 256, 0, stream>>>(bfr);
    kA<<<NPAIR / PPB, 256, 0, stream>>>(x, bfr, avg, mxv, feat);
    kB<<<BB, 256, 0, stream>>>(avg, mxv, feat,
                               w_att1, w_att2, w_bb, b_bb,
                               w_fe1, b_fe1, w_fe2, b_fe2,
                               w_h1, b_h1, w_h2, b_h2, w_h3, b_h3,
                               (float*)d_out);
}